// Round 1
// baseline (10099.297 us; speedup 1.0000x reference)
//
#include <hip/hip_runtime.h>
#include <math.h>

typedef _Float16 f16;
typedef f16 f16x2 __attribute__((ext_vector_type(2)));
typedef f16 f16x4 __attribute__((ext_vector_type(4)));
typedef f16 f16x8 __attribute__((ext_vector_type(8)));
typedef float f32x4 __attribute__((ext_vector_type(4)));

#define HDIM 1024
#define SEQ  2048
#define NBLK 16
#define RPB  64   // rows of W_hh per recurrence block

// ---------------- init: zero flags + hs row 0 ----------------
__global__ void k_init(unsigned* flags, unsigned* hs0) {
  int i = threadIdx.x;
  if (i < 512) { flags[i] = 0; hs0[i] = 0; }
}

// ---------------- f32 -> f16 convert (vec4, grid-stride) ----------------
__global__ void k_cvt(const float* __restrict__ in, f16* __restrict__ out, int n4) {
  int stride = gridDim.x * blockDim.x;
  for (int i = blockIdx.x * blockDim.x + threadIdx.x; i < n4; i += stride) {
    float4 v = ((const float4*)in)[i];
    f16x4 o = { (f16)v.x, (f16)v.y, (f16)v.z, (f16)v.w };
    ((f16x4*)out)[i] = o;
  }
}

__global__ void k_bias(const float* __restrict__ a, const float* __restrict__ b,
                       float* __restrict__ o) {
  int i = blockIdx.x * blockDim.x + threadIdx.x;
  if (i < HDIM) o[i] = a[i] + b[i];
}

// ---------------- B^T GEMM:  C[M][N] = A[M][K=1024] * B[N][K=1024]^T + bias[N]
// 128x128 tile, BK=32, 256 threads (4 waves, 2x2), mfma_f32_16x16x32_f16.
__global__ __launch_bounds__(256) void k_gemm(
    const f16* __restrict__ A, const f16* __restrict__ B,
    const float* __restrict__ bias, float* __restrict__ C, int N)
{
  const int K = 1024;
  __shared__ __align__(16) f16 lsA[128 * 32];
  __shared__ __align__(16) f16 lsB[128 * 32];
  const int tid = threadIdx.x;
  const int l   = tid & 63;
  const int wv  = tid >> 6;
  const int mb  = blockIdx.y * 128;
  const int nb  = blockIdx.x * 128;
  const int wm  = (wv >> 1) * 64;   // wave row offset in tile
  const int wn  = (wv & 1) * 64;    // wave col offset in tile

  f32x4 acc[4][4] = {};

  for (int kt = 0; kt < K; kt += 32) {
    // stage to regs (chunk c: row = c>>2, half-offset = (c&3)*8)
    uint4 ra[2], rb[2];
#pragma unroll
    for (int i = 0; i < 2; ++i) {
      int c = tid + i * 256;
      int row = c >> 2, off = (c & 3) * 8;
      ra[i] = *(const uint4*)(A + (size_t)(mb + row) * K + kt + off);
      rb[i] = *(const uint4*)(B + (size_t)(nb + row) * K + kt + off);
    }
    __syncthreads();   // previous iter's ds_reads done before overwrite
#pragma unroll
    for (int i = 0; i < 2; ++i) {
      int c = tid + i * 256;
      *(uint4*)(lsA + c * 8) = ra[i];
      *(uint4*)(lsB + c * 8) = rb[i];
    }
    __syncthreads();

    f16x8 af[4], bf[4];
#pragma unroll
    for (int m = 0; m < 4; ++m)
      af[m] = *(const f16x8*)(lsA + (wm + m * 16 + (l & 15)) * 32 + (l >> 4) * 8);
#pragma unroll
    for (int n = 0; n < 4; ++n)
      bf[n] = *(const f16x8*)(lsB + (wn + n * 16 + (l & 15)) * 32 + (l >> 4) * 8);
#pragma unroll
    for (int m = 0; m < 4; ++m)
#pragma unroll
      for (int n = 0; n < 4; ++n)
        acc[m][n] = __builtin_amdgcn_mfma_f32_16x16x32_f16(af[m], bf[n], acc[m][n], 0, 0, 0);
  }

  // epilogue: C/D layout col = l&15, row = (l>>4)*4 + j
#pragma unroll
  for (int n = 0; n < 4; ++n) {
    int col = nb + wn + n * 16 + (l & 15);
    float bv = bias[col];
#pragma unroll
    for (int m = 0; m < 4; ++m) {
#pragma unroll
      for (int j = 0; j < 4; ++j) {
        int row = mb + wm + m * 16 + (l >> 4) * 4 + j;
        C[(size_t)row * N + col] = acc[m][n][j] + bv;
      }
    }
  }
}

// ---------------- sequential recurrence: 16 persistent blocks ----------------
// Block b owns rows [b*64, b*64+64) of W_hh (f16 in VGPRs).
// hs has SEQ+1 rows (f16); row 0 = zeros. Step t reads row t-1, writes row t.
// flags[b*32] = highest row written by block b (device-scope).
__global__ __launch_bounds__(1024) void k_recur(
    const float* __restrict__ W,      // W_hh f32 [H][H]
    const float* __restrict__ xp,     // [SEQ][H] f32
    f16* __restrict__ hs,             // [(SEQ+1)][H]
    unsigned* __restrict__ flags)
{
  const int b   = blockIdx.x;
  const int tid = threadIdx.x;
  const int w   = tid >> 6;
  const int l   = tid & 63;
  const int hfl = l >> 5;           // 0/1: which row pair of the wave's 4 rows
  const int ch  = l & 31;           // column chunk (32 cols each)
  const int r0  = b * RPB + w * 4 + hfl * 2;
  const int c0  = ch * 32;

  // load + convert this thread's 2x32 weight slice into packed half2 regs
  f16x2 wv0[16], wv1[16];
  {
    const float* w0 = W + (size_t)r0 * HDIM + c0;
    const float* w1 = w0 + HDIM;
#pragma unroll
    for (int j = 0; j < 16; ++j) {
      wv0[j] = f16x2{ (f16)w0[2 * j], (f16)w0[2 * j + 1] };
      wv1[j] = f16x2{ (f16)w1[2 * j], (f16)w1[2 * j + 1] };
    }
  }

  for (unsigned t = 1; t <= SEQ; ++t) {
    // wait until every block has written row t-1
    unsigned need = t - 1;
    if (tid < NBLK) {
      while (__hip_atomic_load(&flags[tid * 32], __ATOMIC_RELAXED,
                               __HIP_MEMORY_SCOPE_AGENT) < need) { }
    }
    __syncthreads();
    __builtin_amdgcn_fence(__ATOMIC_ACQUIRE, "agent");

    // load h_{t-1} chunk (32 halves = 64B)
    const uint4* hp = (const uint4*)(hs + (size_t)(t - 1) * HDIM + c0);
    f16x2 hv[16];
#pragma unroll
    for (int q = 0; q < 4; ++q) {
      uint4 u = hp[q];
      hv[4 * q + 0] = __builtin_bit_cast(f16x2, u.x);
      hv[4 * q + 1] = __builtin_bit_cast(f16x2, u.y);
      hv[4 * q + 2] = __builtin_bit_cast(f16x2, u.z);
      hv[4 * q + 3] = __builtin_bit_cast(f16x2, u.w);
    }

    float s0 = 0.f, s1 = 0.f;
#pragma unroll
    for (int j = 0; j < 16; ++j) {
      s0 = __builtin_amdgcn_fdot2(wv0[j], hv[j], s0, false);
      s1 = __builtin_amdgcn_fdot2(wv1[j], hv[j], s1, false);
    }
    // reduce over the 32 column-chunk lanes (masks < 32 stay within half-wave)
#pragma unroll
    for (int m = 16; m >= 1; m >>= 1) {
      s0 += __shfl_xor(s0, m, 64);
      s1 += __shfl_xor(s1, m, 64);
    }

    if (ch == 0) {
      const float* xr = xp + (size_t)(t - 1) * HDIM + r0;
      float h0 = tanhf(xr[0] + s0);
      float h1 = tanhf(xr[1] + s1);
      f16x2 hh = { (f16)h0, (f16)h1 };
      *(f16x2*)(hs + (size_t)t * HDIM + r0) = hh;
    }

    __syncthreads();   // all stores drained to L2 before publish
    if (tid == 0) {
      __builtin_amdgcn_fence(__ATOMIC_RELEASE, "agent");
      __hip_atomic_store(&flags[b * 32], t, __ATOMIC_RELAXED,
                         __HIP_MEMORY_SCOPE_AGENT);
    }
  }
}

// ---------------- launch ----------------
extern "C" void kernel_launch(void* const* d_in, const int* in_sizes, int n_in,
                              void* d_out, int out_size, void* d_ws, size_t ws_size,
                              hipStream_t stream) {
  const float* x    = (const float*)d_in[0];   // [1,2048,1024]
  const float* W_ih = (const float*)d_in[1];   // [1024,1024]
  const float* W_hh = (const float*)d_in[2];   // [1024,1024]
  const float* b_ih = (const float*)d_in[3];
  const float* b_hh = (const float*)d_in[4];
  const float* W_fc = (const float*)d_in[5];   // [32000,1024]
  const float* b_fc = (const float*)d_in[6];
  float* out = (float*)d_out;                  // [2048,32000]

  char* ws = (char*)d_ws;
  unsigned* flags = (unsigned*)ws;                           // 2 KB (+pad)
  f16*   hs16  = (f16*)(ws + 4096);                          // 2049*1024*2 = 4196352
  float* xp    = (float*)(ws + 4200448);                     // 2048*1024*4 = 8388608
  f16*   x16   = (f16*)(ws + 12589056);                      // 4194304
  f16*   wih16 = (f16*)(ws + 16783360);                      // 2097152
  f16*   wfc16 = (f16*)(ws + 18880512);                      // 65536000
  float* bsum  = (float*)(ws + 84416512);                    // 4096  (total ~84.4 MB)

  k_init<<<1, 512, 0, stream>>>(flags, (unsigned*)hs16);
  k_cvt<<<1024, 256, 0, stream>>>(x, x16, 2048 * 1024 / 4);
  k_cvt<<<1024, 256, 0, stream>>>(W_ih, wih16, 1024 * 1024 / 4);
  k_cvt<<<2048, 256, 0, stream>>>(W_fc, wfc16, 32000 * 1024 / 4);
  k_bias<<<4, 256, 0, stream>>>(b_ih, b_hh, bsum);

  // xp = x @ W_ih^T + (b_ih + b_hh)   -> f32 [2048][1024]
  k_gemm<<<dim3(8, 16), 256, 0, stream>>>(x16, wih16, bsum, xp, 1024);

  // sequential recurrence -> hs16 rows 1..2048
  k_recur<<<NBLK, 1024, 0, stream>>>(W_hh, xp, hs16, flags);

  // out = hs @ W_fc^T + b_fc   -> f32 [2048][32000]
  k_gemm<<<dim3(250, 16), 256, 0, stream>>>(hs16 + HDIM, wfc16, b_fc, out, 32000);
}

// Round 3
// 6575.948 us; speedup vs baseline: 1.5358x; 1.5358x over previous
//
#include <hip/hip_runtime.h>
#include <math.h>

typedef _Float16 f16;
typedef f16 f16x2 __attribute__((ext_vector_type(2)));
typedef f16 f16x4 __attribute__((ext_vector_type(4)));
typedef f16 f16x8 __attribute__((ext_vector_type(8)));
typedef float f32x4 __attribute__((ext_vector_type(4)));

#define HDIM 1024
#define SEQ  2048
#define NBLK 16
#define RPB  64   // rows of W_hh per recurrence block

// ---------------- clear the (tag,payload) pair array ----------------
// Row 0 cleared to (tag=0, payload=0) doubles as h_0 = 0.
// Rows t>=1 cleared to tag=0 != t so pollers can't accept stale/poisoned data.
__global__ void k_clear(unsigned long long* __restrict__ p, int n) {
  int stride = gridDim.x * blockDim.x;
  for (int i = blockIdx.x * blockDim.x + threadIdx.x; i < n; i += stride)
    p[i] = 0ULL;
}

// ---------------- f32 -> f16 convert (vec4, grid-stride) ----------------
__global__ void k_cvt(const float* __restrict__ in, f16* __restrict__ out, int n4) {
  int stride = gridDim.x * blockDim.x;
  for (int i = blockIdx.x * blockDim.x + threadIdx.x; i < n4; i += stride) {
    float4 v = ((const float4*)in)[i];
    f16x4 o = { (f16)v.x, (f16)v.y, (f16)v.z, (f16)v.w };
    ((f16x4*)out)[i] = o;
  }
}

__global__ void k_bias(const float* __restrict__ a, const float* __restrict__ b,
                       float* __restrict__ o) {
  int i = blockIdx.x * blockDim.x + threadIdx.x;
  if (i < HDIM) o[i] = a[i] + b[i];
}

// ---------------- B^T GEMM:  C[M][N] = A[M][K=1024] * B[N][K=1024]^T + bias[N]
// 128x128 tile, BK=32, 256 threads (4 waves, 2x2), mfma_f32_16x16x32_f16.
__global__ __launch_bounds__(256) void k_gemm(
    const f16* __restrict__ A, const f16* __restrict__ B,
    const float* __restrict__ bias, float* __restrict__ C, int N)
{
  const int K = 1024;
  __shared__ __align__(16) f16 lsA[128 * 32];
  __shared__ __align__(16) f16 lsB[128 * 32];
  const int tid = threadIdx.x;
  const int l   = tid & 63;
  const int wv  = tid >> 6;
  const int mb  = blockIdx.y * 128;
  const int nb  = blockIdx.x * 128;
  const int wm  = (wv >> 1) * 64;   // wave row offset in tile
  const int wn  = (wv & 1) * 64;    // wave col offset in tile

  f32x4 acc[4][4] = {};

  for (int kt = 0; kt < K; kt += 32) {
    // stage to regs (chunk c: row = c>>2, half-offset = (c&3)*8)
    uint4 ra[2], rb[2];
#pragma unroll
    for (int i = 0; i < 2; ++i) {
      int c = tid + i * 256;
      int row = c >> 2, off = (c & 3) * 8;
      ra[i] = *(const uint4*)(A + (size_t)(mb + row) * K + kt + off);
      rb[i] = *(const uint4*)(B + (size_t)(nb + row) * K + kt + off);
    }
    __syncthreads();   // previous iter's ds_reads done before overwrite
#pragma unroll
    for (int i = 0; i < 2; ++i) {
      int c = tid + i * 256;
      *(uint4*)(lsA + c * 8) = ra[i];
      *(uint4*)(lsB + c * 8) = rb[i];
    }
    __syncthreads();

    f16x8 af[4], bf[4];
#pragma unroll
    for (int m = 0; m < 4; ++m)
      af[m] = *(const f16x8*)(lsA + (wm + m * 16 + (l & 15)) * 32 + (l >> 4) * 8);
#pragma unroll
    for (int n = 0; n < 4; ++n)
      bf[n] = *(const f16x8*)(lsB + (wn + n * 16 + (l & 15)) * 32 + (l >> 4) * 8);
#pragma unroll
    for (int m = 0; m < 4; ++m)
#pragma unroll
      for (int n = 0; n < 4; ++n)
        acc[m][n] = __builtin_amdgcn_mfma_f32_16x16x32_f16(af[m], bf[n], acc[m][n], 0, 0, 0);
  }

  // epilogue: C/D layout col = l&15, row = (l>>4)*4 + j
#pragma unroll
  for (int n = 0; n < 4; ++n) {
    int col = nb + wn + n * 16 + (l & 15);
    float bv = bias[col];
#pragma unroll
    for (int m = 0; m < 4; ++m) {
#pragma unroll
      for (int j = 0; j < 4; ++j) {
        int row = mb + wm + m * 16 + (l >> 4) * 4 + j;
        C[(size_t)row * N + col] = acc[m][n][j] + bv;
      }
    }
  }
}

// ---------------- sequential recurrence: 16 persistent blocks ----------------
// Tag-in-data scheme (no fences, no flag round-trip): h row t word w holds
// (tag=t)<<32 | f16x2 payload, stored/loaded as relaxed agent-scope 64-bit
// atomics (single-copy atomic, coherent at MALL).
// POLL DISCIPLINE (R2 lesson): only wave 0 polls (64 lanes x 8 words), then
// broadcasts the row to the other 15 waves via LDS. The poll on our own
// block's 32 words doubles as the intra-block barrier: our writers store row
// t only after their waves' LDS reads of row t-1 completed (shfl-reduce data
// dependency), so wave 0 passing the poll implies hl[] is safe to overwrite.
__global__ __launch_bounds__(1024) void k_recur(
    const float* __restrict__ W,              // W_hh f32 [H][H]
    const float* __restrict__ xp,             // [SEQ][H] f32
    unsigned long long* __restrict__ pairs,   // [(SEQ+1)*512]
    f16* __restrict__ hs)                     // [(SEQ+1)][H] clean copy
{
  // swizzled LDS: word w -> hl[(w>>4)*17 + (w&15)]  (17-stride kills bank conflicts)
  __shared__ unsigned hl[544];

  const int b   = blockIdx.x;
  const int tid = threadIdx.x;
  const int w   = tid >> 6;
  const int l   = tid & 63;
  const int hfl = l >> 5;           // 0/1: which row pair of the wave's 4 rows
  const int ch  = l & 31;           // column chunk (32 cols each)
  const int r0  = b * RPB + w * 4 + hfl * 2;
  const int c0  = ch * 32;

  // load + convert this thread's 2x32 weight slice into packed half2 regs
  f16x2 wv0[16], wv1[16];
  {
    const float* w0 = W + (size_t)r0 * HDIM + c0;
    const float* w1 = w0 + HDIM;
#pragma unroll
    for (int j = 0; j < 16; ++j) {
      wv0[j] = f16x2{ (f16)w0[2 * j], (f16)w0[2 * j + 1] };
      wv1[j] = f16x2{ (f16)w1[2 * j], (f16)w1[2 * j + 1] };
    }
  }

  const bool poller = (w == 0);
  bool dead = false;                 // hang-proofing: latch on poll timeout

  for (unsigned t = 1; t <= SEQ; ++t) {
    // prefetch xp early (independent -> hides under poll/barrier)
    float x0 = 0.f, x1 = 0.f;
    if (ch == 0) {
      const float* xr = xp + (size_t)(t - 1) * HDIM + r0;
      x0 = xr[0]; x1 = xr[1];
    }

    if (poller) {
      // lane l owns words l*8 .. l*8+7 of row t-1
      const unsigned long long* row = pairs + (size_t)(t - 1) * 512 + l * 8;
      const unsigned need = t - 1;
      unsigned long long u[8];
      if (!dead) {
        int guard = 0;
        for (;;) {
          bool ok = true;
#pragma unroll
          for (int j = 0; j < 8; ++j)
            u[j] = __hip_atomic_load(row + j, __ATOMIC_RELAXED,
                                     __HIP_MEMORY_SCOPE_AGENT);
#pragma unroll
          for (int j = 0; j < 8; ++j)
            ok &= ((unsigned)(u[j] >> 32) == need);
          if (ok) break;
          if (++guard > (1 << 22)) { dead = true; break; }  // ~1s, once
        }
      } else {
#pragma unroll
        for (int j = 0; j < 8; ++j) u[j] = 0ULL;
      }
      // deposit payloads in LDS (words l*8+j -> chunk l>>1, sub (l&1)*8+j)
      const int base = (l >> 1) * 17 + (l & 1) * 8;
#pragma unroll
      for (int j = 0; j < 8; ++j) hl[base + j] = (unsigned)u[j];
    }
    __syncthreads();

    // every thread reads its 16 payload words: chunk ch -> hl[ch*17 + j]
    float s0 = 0.f, s1 = 0.f;
#pragma unroll
    for (int j = 0; j < 16; ++j) {
      f16x2 hv = __builtin_bit_cast(f16x2, hl[ch * 17 + j]);
      s0 = __builtin_amdgcn_fdot2(wv0[j], hv, s0, false);
      s1 = __builtin_amdgcn_fdot2(wv1[j], hv, s1, false);
    }
    // reduce over the 32 column-chunk lanes (masks < 32 stay within half-wave)
#pragma unroll
    for (int m = 16; m >= 1; m >>= 1) {
      s0 += __shfl_xor(s0, m, 64);
      s1 += __shfl_xor(s1, m, 64);
    }

    if (ch == 0) {
      float h0 = tanhf(x0 + s0);
      float h1 = tanhf(x1 + s1);
      f16x2 hh = { (f16)h0, (f16)h1 };
      unsigned pay = __builtin_bit_cast(unsigned, hh);
      unsigned long long val = ((unsigned long long)t << 32) | (unsigned long long)pay;
      __hip_atomic_store(pairs + (size_t)t * 512 + (r0 >> 1), val,
                         __ATOMIC_RELAXED, __HIP_MEMORY_SCOPE_AGENT);
      // clean copy for the head GEMM (visible after kernel-boundary flush)
      *(f16x2*)(hs + (size_t)t * HDIM + r0) = hh;
    }
  }
}

// ---------------- launch ----------------
extern "C" void kernel_launch(void* const* d_in, const int* in_sizes, int n_in,
                              void* d_out, int out_size, void* d_ws, size_t ws_size,
                              hipStream_t stream) {
  const float* x    = (const float*)d_in[0];   // [1,2048,1024]
  const float* W_ih = (const float*)d_in[1];   // [1024,1024]
  const float* W_hh = (const float*)d_in[2];   // [1024,1024]
  const float* b_ih = (const float*)d_in[3];
  const float* b_hh = (const float*)d_in[4];
  const float* W_fc = (const float*)d_in[5];   // [32000,1024]
  const float* b_fc = (const float*)d_in[6];
  float* out = (float*)d_out;                  // [2048,32000]

  char* ws = (char*)d_ws;
  unsigned long long* pairs = (unsigned long long*)ws;       // 2049*512*8 = 8,392,704
  f16*   hs16  = (f16*)(ws + 8500000);                       // 2049*1024*2 = 4,196,352
  float* xp    = (float*)(ws + 12700000);                    // 2048*1024*4 = 8,388,608
  f16*   x16   = (f16*)(ws + 21100000);                      // 4,194,304
  f16*   wih16 = (f16*)(ws + 25300000);                      // 2,097,152
  f16*   wfc16 = (f16*)(ws + 27400000);                      // 65,536,000
  float* bsum  = (float*)(ws + 92936000);                    // 4,096  (total ~92.9 MB)

  k_clear<<<1024, 256, 0, stream>>>(pairs, (SEQ + 1) * 512);
  k_cvt<<<1024, 256, 0, stream>>>(x, x16, 2048 * 1024 / 4);
  k_cvt<<<1024, 256, 0, stream>>>(W_ih, wih16, 1024 * 1024 / 4);
  k_cvt<<<2048, 256, 0, stream>>>(W_fc, wfc16, 32000 * 1024 / 4);
  k_bias<<<4, 256, 0, stream>>>(b_ih, b_hh, bsum);

  // xp = x @ W_ih^T + (b_ih + b_hh)   -> f32 [2048][1024]
  k_gemm<<<dim3(8, 16), 256, 0, stream>>>(x16, wih16, bsum, xp, 1024);

  // sequential recurrence -> pairs rows 1..2048 + clean hs16
  k_recur<<<NBLK, 1024, 0, stream>>>(W_hh, xp, pairs, hs16);

  // out = hs @ W_fc^T + b_fc   -> f32 [2048][32000]
  k_gemm<<<dim3(250, 16), 256, 0, stream>>>(hs16 + HDIM, wfc16, b_fc, out, 32000);
}